// Round 5
// baseline (2575.703 us; speedup 1.0000x reference)
//
#include <hip/hip_runtime.h>
#include <math.h>

#define CIN   3
#define DD    32
#define HH    128
#define WW    128
#define COUTC 24
#define HP    126
#define WP    126
#define PLANE (HH * WW)            // 16384

#define NTH     512                // 8 waves: 4 channels x 2 row-halves
#define LDSROW  68                 // floats per staged row (17 float4)
#define RPC     10                 // input rows per cin (8 out rows + 2)
#define SLICE_F (CIN * RPC * LDSROW)   // 2040 floats per slice buffer
#define NSLOT   (CIN * RPC * 17)   // 510 float4 staging slots

// One depth slice. Slot of conv[j] = j%3. At slice d: S0=d%3 (zeroed, kd=0),
// S1=(d+2)%3 (kd=1 -> conv[d-1]), S2=(d+1)%3 (kd=2 -> completes conv[d-2]).
// Garbage accumulated into not-yet-valid / past-end slots is never min'd.
template<int S0, int S1, int S2>
__device__ __forceinline__ void do_slice(
    int d,
    const float* __restrict__ gsrc, int stg_act, int lds_woff, float4& st,
    const float (&w)[81], float (&ring)[4][3], float (&mn)[4],
    const float* __restrict__ rbase,      // lane's read base in buffer 0
    float* __restrict__ lds)
{
  // issue next slice's global load early; latency hides under this compute
  if (stg_act && (d + 1) < DD)
    st = *(const float4*)(gsrc + (size_t)(d + 1) * PLANE);

  __syncthreads();                        // buf[d&1] fully staged

  const float* bp = rbase + (d & 1) * SLICE_F;

  #pragma unroll
  for (int q = 0; q < 4; ++q) ring[q][S0] = 0.0f;

  #pragma unroll
  for (int ci = 0; ci < CIN; ++ci) {
    #pragma unroll
    for (int kh = 0; kh < 3; ++kh) {
      // row/ci/kh offsets are compile-time -> fold into ds_read immediates
      const float* rp = bp + (ci * RPC + kh) * LDSROW;
      float4 a  = *(const float4*)rp;
      float2 b2 = *(const float2*)(rp + 4);
      float p[6] = {a.x, a.y, a.z, a.w, b2.x, b2.y};
      #pragma unroll
      for (int kw = 0; kw < 3; ++kw) {
        const float wv0 = w[ci * 27 + 0 + kh * 3 + kw];    // kd=0
        const float wv1 = w[ci * 27 + 9 + kh * 3 + kw];    // kd=1
        const float wv2 = w[ci * 27 + 18 + kh * 3 + kw];   // kd=2
        #pragma unroll
        for (int q = 0; q < 4; ++q) {
          const float xv = p[kw + q];
          ring[q][S0] = fmaf(xv, wv0, ring[q][S0]);
          ring[q][S1] = fmaf(xv, wv1, ring[q][S1]);
          ring[q][S2] = fmaf(xv, wv2, ring[q][S2]);
        }
      }
    }
  }

  if (d >= 2) {                           // S2 = completed conv[d-2]
    #pragma unroll
    for (int q = 0; q < 4; ++q) mn[q] = fminf(mn[q], ring[q][S2]);
  }

  if (stg_act && (d + 1) < DD)
    *(float4*)(lds + ((d + 1) & 1) * SLICE_F + lds_woff) = st;
}

__global__ void __launch_bounds__(NTH, 2)
conv3d_min_kernel(const float* __restrict__ x,
                  const float* __restrict__ wgt,
                  const float* __restrict__ bias,
                  float* __restrict__ out)
{
  __shared__ __align__(16) float lds[2 * SLICE_F];   // 16.3 KB

  const int t    = threadIdx.x;
  const int lane = t & 63;
  const int wv   = t >> 6;                 // 8 waves
  const int ch   = blockIdx.y * 4 + (wv >> 1);
  const int rh   = wv & 1;                 // row-half of the 8-row tile
  const int r    = lane >> 4;              // 0..3
  const int g    = lane & 15;              // col-group (4 cols)
  const int rowloc = rh * 4 + r;           // 0..7 within tile
  const int wt   = blockIdx.x & 1;
  const int ht   = blockIdx.x >> 1;        // 16 h-tiles of 8 rows
  const int bb   = blockIdx.z;
  const int hp0  = ht * 8;
  const int w0   = wt * 64;

  // ---- channel weights -> VGPRs, raw layout [ci][kd][kh][kw] ----
  float w[81];
  {
    const float* wc = wgt + ch * 81;
    #pragma unroll
    for (int i = 0; i < 81; ++i) w[i] = wc[i];
  }

  // ---- staging: exactly one float4 slot per thread (510 of 512 active) ----
  const int stg_act = (t < NSLOT);
  const int srow = t / 17;                 // 0..29
  const int sj   = t - srow * 17;          // 0..16
  const int sci  = srow / RPC;
  const int srr  = srow - sci * RPC;
  int grow = hp0 + srr; grow = grow > 127 ? 127 : grow;   // clamp: feeds only invalid rows
  int gcol = w0 + sj * 4; gcol = gcol > 124 ? 124 : gcol; // clamp keeps 16B align
  const float* gsrc = x + (size_t)(bb * CIN + sci) * (DD * PLANE)
                        + (size_t)grow * WW + gcol;
  const int lds_woff = srow * LDSROW + sj * 4;

  // lane's LDS read base (buffer 0): its input row rowloc, col 4g
  const float* rbase = lds + rowloc * LDSROW + g * 4;

  float ring[4][3];
  float mn[4];
  #pragma unroll
  for (int q = 0; q < 4; ++q) {
    mn[q] = INFINITY;
    ring[q][0] = ring[q][1] = ring[q][2] = 0.0f;
  }

  // ---- prologue: stage slice 0 into buffer 0 ----
  float4 st = make_float4(0.f, 0.f, 0.f, 0.f);
  if (stg_act) {
    st = *(const float4*)gsrc;
    *(float4*)(lds + lds_woff) = st;
  }

  // ---- stream 32 slices; ring slots compile-time (period 3) ----
  for (int d0 = 0; d0 < 30; d0 += 3) {
    do_slice<0,2,1>(d0,     gsrc, stg_act, lds_woff, st, w, ring, mn, rbase, lds);
    do_slice<1,0,2>(d0 + 1, gsrc, stg_act, lds_woff, st, w, ring, mn, rbase, lds);
    do_slice<2,1,0>(d0 + 2, gsrc, stg_act, lds_woff, st, w, ring, mn, rbase, lds);
  }
  do_slice<0,2,1>(30, gsrc, stg_act, lds_woff, st, w, ring, mn, rbase, lds);
  do_slice<1,0,2>(31, gsrc, stg_act, lds_woff, st, w, ring, mn, rbase, lds);

  // ---- epilogue: bias + store logits (softmax = kernel 2) ----
  const float bval = bias[ch];
  const int orow = hp0 + rowloc;
  if (orow < HP) {
    const int ocol = w0 + g * 4;
    float* op = out + ((size_t)(bb * COUTC + ch) * HP + orow) * WP + ocol;
    if (ocol + 3 < WP) {
      float4 o = make_float4(mn[0] + bval, mn[1] + bval,
                             mn[2] + bval, mn[3] + bval);
      *(float4*)op = o;
    } else {
      #pragma unroll
      for (int cc = 0; cc < 4; ++cc)
        if (ocol + cc < WP) op[cc] = mn[cc] + bval;
    }
  }
}

// ---- kernel 2: in-place softmax over the 24 channels ----
__global__ void __launch_bounds__(256)
softmax_ch_kernel(float* __restrict__ out)
{
  const int idx = blockIdx.x * 256 + threadIdx.x;
  const int npx = 16 * HP * WP;            // 254016
  if (idx >= npx) return;
  const int b  = idx / (HP * WP);
  const int hw = idx - b * (HP * WP);
  float* p = out + (size_t)b * COUTC * HP * WP + hw;

  float v[COUTC];
  float mx = -INFINITY;
  #pragma unroll
  for (int c = 0; c < COUTC; ++c) {
    v[c] = p[(size_t)c * HP * WP];
    mx = fmaxf(mx, v[c]);
  }
  float s = 0.0f;
  #pragma unroll
  for (int c = 0; c < COUTC; ++c) {
    v[c] = __expf(v[c] - mx);
    s += v[c];
  }
  const float r = 1.0f / s;
  #pragma unroll
  for (int c = 0; c < COUTC; ++c)
    p[(size_t)c * HP * WP] = v[c] * r;
}

extern "C" void kernel_launch(void* const* d_in, const int* in_sizes, int n_in,
                              void* d_out, int out_size, void* d_ws, size_t ws_size,
                              hipStream_t stream)
{
  const float* x    = (const float*)d_in[0];
  const float* wgt  = (const float*)d_in[1];
  const float* bias = (const float*)d_in[2];
  float* out = (float*)d_out;

  dim3 grid1(32, 6, 16);                   // (wt+ht, ch-group, batch)
  hipLaunchKernelGGL(conv3d_min_kernel, grid1, dim3(NTH), 0, stream,
                     x, wgt, bias, out);

  const int npx = 16 * HP * WP;
  dim3 grid2((npx + 255) / 256);
  hipLaunchKernelGGL(softmax_ch_kernel, grid2, dim3(256), 0, stream, out);
}

// Round 6
// 646.897 us; speedup vs baseline: 3.9816x; 3.9816x over previous
//
#include <hip/hip_runtime.h>
#include <math.h>

#define CIN   3
#define DD    32
#define HH    128
#define WW    128
#define COUTC 24
#define HP    126
#define WP    126
#define PLANE (HH * WW)            // 16384

#define NTH     512                // 8 waves: 4 channels x 2 row-halves
#define LDSROW  68                 // floats per staged row (17 float4)
#define RPC     10                 // input rows per cin (8 out rows + 2)
#define SLICE_F (CIN * RPC * LDSROW)   // 2040 floats per slice buffer
#define NSLOT   (CIN * RPC * 17)   // 510 float4 staging slots

// One depth slice. Slot of conv[j] = j%3. At slice d: S0=d%3 (zeroed, kd=0),
// S1=(d+2)%3 (kd=1 -> conv[d-1]), S2=(d+1)%3 (kd=2 -> completes conv[d-2]).
template<int S0, int S1, int S2>
__device__ __forceinline__ void do_slice(
    int d,
    const float* __restrict__ gsrc, int stg_act, int lds_woff, float4& st,
    const float (&w)[81],            // wave-uniform -> SGPRs
    float (&ring)[4][3], float (&mn)[4],
    const float* __restrict__ rbase,
    float* __restrict__ lds)
{
  if (stg_act && (d + 1) < DD)
    st = *(const float4*)(gsrc + (size_t)(d + 1) * PLANE);

  __syncthreads();                        // buf[d&1] fully staged

  const float* bp = rbase + (d & 1) * SLICE_F;

  #pragma unroll
  for (int q = 0; q < 4; ++q) ring[q][S0] = 0.0f;

  #pragma unroll
  for (int ci = 0; ci < CIN; ++ci) {
    #pragma unroll
    for (int kh = 0; kh < 3; ++kh) {
      // two b128 reads (conflict-free full-bank coverage); 8 dwords, 6 used
      const float* rp = bp + (ci * RPC + kh) * LDSROW;
      float4 a = *(const float4*)rp;
      float4 b = *(const float4*)(rp + 4);
      float p[8] = {a.x, a.y, a.z, a.w, b.x, b.y, b.z, b.w};
      #pragma unroll
      for (int kw = 0; kw < 3; ++kw) {
        const float wv0 = w[ci * 27 + 0 + kh * 3 + kw];    // kd=0 -> S0
        const float wv1 = w[ci * 27 + 9 + kh * 3 + kw];    // kd=1 -> S1
        const float wv2 = w[ci * 27 + 18 + kh * 3 + kw];   // kd=2 -> S2
        #pragma unroll
        for (int q = 0; q < 4; ++q) {
          const float xv = p[kw + q];
          ring[q][S0] = fmaf(xv, wv0, ring[q][S0]);
          ring[q][S1] = fmaf(xv, wv1, ring[q][S1]);
          ring[q][S2] = fmaf(xv, wv2, ring[q][S2]);
        }
      }
    }
  }

  if (d >= 2) {
    #pragma unroll
    for (int q = 0; q < 4; ++q) mn[q] = fminf(mn[q], ring[q][S2]);
  }

  if (stg_act && (d + 1) < DD)
    *(float4*)(lds + ((d + 1) & 1) * SLICE_F + lds_woff) = st;
}

__global__ void __launch_bounds__(NTH, 2)
conv3d_min_kernel(const float* __restrict__ x,
                  const float* __restrict__ wgt,
                  const float* __restrict__ bias,
                  float* __restrict__ out)
{
  __shared__ __align__(16) float lds[2 * SLICE_F];   // 16.3 KB

  const int t    = threadIdx.x;
  const int lane = t & 63;
  const int wv   = t >> 6;                 // 8 waves
  // channel is wave-uniform: force to SGPR so weight loads become s_load
  const int ch   = __builtin_amdgcn_readfirstlane(blockIdx.y * 4 + (wv >> 1));
  const int rh   = wv & 1;                 // row-half of the 8-row tile
  const int r    = lane >> 4;              // 0..3
  const int g    = lane & 15;              // col-group (4 cols)
  const int rowloc = rh * 4 + r;           // 0..7 within tile
  const int wt   = blockIdx.x & 1;
  const int ht   = blockIdx.x >> 1;        // 16 h-tiles of 8 rows
  const int bb   = blockIdx.z;
  const int hp0  = ht * 8;
  const int w0   = wt * 64;

  // ---- channel weights (wave-uniform -> SGPR file) ----
  float w[81];
  {
    const float* wc = wgt + ch * 81;
    #pragma unroll
    for (int i = 0; i < 81; ++i) w[i] = wc[i];
  }
  const float bval = bias[ch];

  // ---- staging: one float4 slot per thread (510 of 512 active) ----
  const int stg_act = (t < NSLOT);
  const int srow = t / 17;                 // 0..29
  const int sj   = t - srow * 17;          // 0..16
  const int sci  = srow / RPC;
  const int srr  = srow - sci * RPC;
  int grow = hp0 + srr; grow = grow > 127 ? 127 : grow;   // feeds only invalid rows
  int gcol = w0 + sj * 4; gcol = gcol > 124 ? 124 : gcol; // keeps 16B align
  const float* gsrc = x + (size_t)(bb * CIN + sci) * (DD * PLANE)
                        + (size_t)grow * WW + gcol;
  const int lds_woff = srow * LDSROW + sj * 4;

  const float* rbase = lds + rowloc * LDSROW + g * 4;

  float ring[4][3];
  float mn[4];
  #pragma unroll
  for (int q = 0; q < 4; ++q) {
    mn[q] = INFINITY;
    ring[q][0] = ring[q][1] = ring[q][2] = 0.0f;
  }

  // ---- prologue: stage slice 0 into buffer 0 ----
  float4 st = make_float4(0.f, 0.f, 0.f, 0.f);
  if (stg_act) {
    st = *(const float4*)gsrc;
    *(float4*)(lds + lds_woff) = st;
  }

  // ---- stream 32 slices; ring slots compile-time (period 3) ----
  for (int d0 = 0; d0 < 30; d0 += 3) {
    do_slice<0,2,1>(d0,     gsrc, stg_act, lds_woff, st, w, ring, mn, rbase, lds);
    do_slice<1,0,2>(d0 + 1, gsrc, stg_act, lds_woff, st, w, ring, mn, rbase, lds);
    do_slice<2,1,0>(d0 + 2, gsrc, stg_act, lds_woff, st, w, ring, mn, rbase, lds);
  }
  do_slice<0,2,1>(30, gsrc, stg_act, lds_woff, st, w, ring, mn, rbase, lds);
  do_slice<1,0,2>(31, gsrc, stg_act, lds_woff, st, w, ring, mn, rbase, lds);

  // ---- epilogue: bias + store logits (softmax = kernel 2) ----
  const int orow = hp0 + rowloc;
  if (orow < HP) {
    const int ocol = w0 + g * 4;
    float* op = out + ((size_t)(bb * COUTC + ch) * HP + orow) * WP + ocol;
    if (ocol + 3 < WP) {
      float4 o = make_float4(mn[0] + bval, mn[1] + bval,
                             mn[2] + bval, mn[3] + bval);
      *(float4*)op = o;
    } else {
      #pragma unroll
      for (int cc = 0; cc < 4; ++cc)
        if (ocol + cc < WP) op[cc] = mn[cc] + bval;
    }
  }
}

// ---- kernel 2: in-place softmax over the 24 channels ----
__global__ void __launch_bounds__(256)
softmax_ch_kernel(float* __restrict__ out)
{
  const int idx = blockIdx.x * 256 + threadIdx.x;
  const int npx = 16 * HP * WP;            // 254016
  if (idx >= npx) return;
  const int b  = idx / (HP * WP);
  const int hw = idx - b * (HP * WP);
  float* p = out + (size_t)b * COUTC * HP * WP + hw;

  float v[COUTC];
  float mx = -INFINITY;
  #pragma unroll
  for (int c = 0; c < COUTC; ++c) {
    v[c] = p[(size_t)c * HP * WP];
    mx = fmaxf(mx, v[c]);
  }
  float s = 0.0f;
  #pragma unroll
  for (int c = 0; c < COUTC; ++c) {
    v[c] = __expf(v[c] - mx);
    s += v[c];
  }
  const float r = 1.0f / s;
  #pragma unroll
  for (int c = 0; c < COUTC; ++c)
    p[(size_t)c * HP * WP] = v[c] * r;
}

extern "C" void kernel_launch(void* const* d_in, const int* in_sizes, int n_in,
                              void* d_out, int out_size, void* d_ws, size_t ws_size,
                              hipStream_t stream)
{
  const float* x    = (const float*)d_in[0];
  const float* wgt  = (const float*)d_in[1];
  const float* bias = (const float*)d_in[2];
  float* out = (float*)d_out;

  dim3 grid1(32, 6, 16);                   // (wt+ht, ch-group, batch)
  hipLaunchKernelGGL(conv3d_min_kernel, grid1, dim3(NTH), 0, stream,
                     x, wgt, bias, out);

  const int npx = 16 * HP * WP;
  dim3 grid2((npx + 255) / 256);
  hipLaunchKernelGGL(softmax_ch_kernel, grid2, dim3(256), 0, stream, out);
}